// Round 21
// baseline (241.489 us; speedup 1.0000x reference)
//
#include <hip/hip_runtime.h>
#include <math.h>

#define B_   2
#define T_   2048
#define DIM_ 1040
#define H_   16
#define HD_  64
#define HD1_ 65
#define NELEM (B_*T_*DIM_)

#define KP_   1056           // GEMM K padded (1040 -> 1056 = 11*96)
#define NP_   1152           // weight rows padded to mult of 128
#define NP3_  3456           // 3*NP_ : fused QKV weight rows
#define SEGS_ 132            // KP_/8
#define MROWS_ (B_*T_)       // 4096

#define NBH_  (B_*H_)        // 32
#define VTR_  72             // VT rows per bh (65 real + row65=ones + zeros)
#define QKW_  96             // QB/KB row width: 64 spatial + 3 Lorentz + pad

// prep_all fused ranges
#define PR_A_ (NP3_*SEGS_)                 // Wb3:   456192
#define PR_B_ (PR_A_ + MROWS_*SEGS_)       // xb:    996864
#define PR_C_ (PR_B_ + NBH_*7*256)         // VT tail: 1054208
#define PR_D_ (PR_C_ + NP_*SEGS_)          // WpB:  1206272

typedef __attribute__((ext_vector_type(8))) __bf16 bf16x8;
typedef __attribute__((ext_vector_type(4))) float f32x4;
typedef __attribute__((ext_vector_type(8))) unsigned short ushort8;

static __device__ __forceinline__ unsigned pack_bf16(float lo, float hi) {
    __bf16 a = (__bf16)lo, c = (__bf16)hi;
    unsigned short ua, uc;
    __builtin_memcpy(&ua, &a, 2);
    __builtin_memcpy(&uc, &c, 2);
    return ((unsigned)uc << 16) | ua;
}

static __device__ __forceinline__ float exp2_fast(float x) {
    float r;
    asm("v_exp_f32 %0, %1" : "=v"(r) : "v"(x));
    return r;
}

// ---------------------------------------------------------------------------
// Plain-bf16 row converter: rows/cols padded with zeros.
// ---------------------------------------------------------------------------
static __device__ __forceinline__ void conv_row_plain(
    const float* __restrict__ in, __bf16* __restrict__ out, int r, int s,
    int rows_in)
{
    float v[8];
    if (r < rows_in && s < 130) {           // 130*8 = 1040 exactly
        const float4 f0 = *(const float4*)(in + (size_t)r * DIM_ + s * 8);
        const float4 f1 = *(const float4*)(in + (size_t)r * DIM_ + s * 8 + 4);
        v[0]=f0.x; v[1]=f0.y; v[2]=f0.z; v[3]=f0.w;
        v[4]=f1.x; v[5]=f1.y; v[6]=f1.z; v[7]=f1.w;
    } else {
        #pragma unroll
        for (int i = 0; i < 8; ++i) v[i] = 0.0f;
    }
    __bf16 t[8] __attribute__((aligned(16)));
    #pragma unroll
    for (int i = 0; i < 8; ++i) t[i] = (__bf16)v[i];
    *(ushort8*)(out) = *(const ushort8*)(t);
}

// ---------------------------------------------------------------------------
// Fused prep: Wq|Wk|Wv -> Wb3, x -> xb, VT tail rows (row65 = ones for the
// free softmax denominator), Wp -> WpB.  All plain bf16, one launch.
// xb doubles as yb later; zero cols 1040..1055 survive attn.
// ---------------------------------------------------------------------------
__global__ __launch_bounds__(256)
void prep_all(const float* __restrict__ x,  const float* __restrict__ Wq,
              const float* __restrict__ Wk, const float* __restrict__ Wv,
              const float* __restrict__ Wp, __bf16* __restrict__ xb,
              __bf16* __restrict__ Wb3, __bf16* __restrict__ VT,
              __bf16* __restrict__ WpB)
{
    const int gid = blockIdx.x * 256 + threadIdx.x;
    if (gid < PR_A_) {
        const int r = gid / SEGS_, s = gid - r * SEGS_;
        const int seg = r / NP_, rr = r - seg * NP_;
        const float* in = (seg == 0) ? Wq : (seg == 1) ? Wk : Wv;
        conv_row_plain(in, Wb3 + (size_t)r * KP_ + s * 8, rr, s, DIM_);
    } else if (gid < PR_B_) {
        const int g = gid - PR_A_;
        const int r = g / SEGS_, s = g - r * SEGS_;
        conv_row_plain(x, xb + (size_t)r * KP_ + s * 8, r, s, MROWS_);
    } else if (gid < PR_C_) {
        const int cid = gid - PR_B_;
        const int bh  = cid / 1792;
        const int rem = cid - bh * 1792;
        const int row = 65 + rem / 256;
        const int tc  = rem - (row - 65) * 256;
        const unsigned val = (row == 65) ? 0x3F803F80u : 0u;
        unsigned* p = (unsigned*)(VT + ((size_t)bh * VTR_ + row) * T_ + tc * 8);
        p[0] = val; p[1] = val; p[2] = val; p[3] = val;
    } else {
        const int g = gid - PR_C_;
        const int r = g / SEGS_, s = g - r * SEGS_;
        conv_row_plain(Wp, WpB + (size_t)r * KP_ + s * 8, r, s, DIM_);
    }
}

// ---------------------------------------------------------------------------
// global->LDS async 16B
// ---------------------------------------------------------------------------
__device__ __forceinline__ void gload_lds16(const void* g, void* l) {
    __builtin_amdgcn_global_load_lds(
        (const __attribute__((address_space(1))) void*)g,
        (__attribute__((address_space(3))) void*)l, 16, 0, 0);
}

// ---------------------------------------------------------------------------
// PURE GEMM core (both operands pre-converted bf16, row stride KP_):
// barrier / 12x global_load_lds / barrier / 48 MFMA per 96-wide K-step.
// ---------------------------------------------------------------------------
#define GEMM_PURE_CORE(Ac_, Bw_, N0_, M0_)                                    \
    __shared__ __bf16 As[128 * 96];                                           \
    __shared__ __bf16 Bs[128 * 96];                                           \
    const int tid  = threadIdx.x;                                             \
    const int lane = tid & 63;                                                \
    const int w    = tid >> 6;                                                \
    const int wr   = (w >> 1) * 64, wc = (w & 1) * 64;                        \
    const __bf16* gap[6]; const __bf16* gb[6];                                \
    _Pragma("unroll")                                                         \
    for (int qi = 0; qi < 6; ++qi) {                                          \
        const int cid = qi * 256 + tid;                                       \
        const int rr  = cid / 12, cc = cid - rr * 12;                         \
        gap[qi] = Ac_ + (size_t)(M0_ + rr) * KP_ + cc * 8;                    \
        gb[qi]  = Bw_ + (size_t)(N0_ + rr) * KP_ + cc * 8;                    \
    }                                                                         \
    f32x4 acc[4][4];                                                          \
    _Pragma("unroll")                                                         \
    for (int i = 0; i < 4; ++i)                                               \
        _Pragma("unroll")                                                     \
        for (int j = 0; j < 4; ++j) acc[i][j] = (f32x4){0.f, 0.f, 0.f, 0.f};  \
    const __bf16* pa = As + (wr + (lane & 15)) * 96 + (lane >> 4) * 8;        \
    const __bf16* pb = Bs + (wc + (lane & 15)) * 96 + (lane >> 4) * 8;        \
    for (int k0 = 0; k0 < KP_; k0 += 96) {                                    \
        __syncthreads();                                                      \
        _Pragma("unroll")                                                     \
        for (int qi = 0; qi < 6; ++qi) {                                      \
            gload_lds16(gap[qi] + k0, As + (qi * 256 + tid) * 8);             \
            gload_lds16(gb[qi]  + k0, Bs + (qi * 256 + tid) * 8);             \
        }                                                                     \
        __syncthreads();                                                      \
        _Pragma("unroll")                                                     \
        for (int ks = 0; ks < 3; ++ks) {                                      \
            bf16x8 a[4], b[4];                                                \
            _Pragma("unroll")                                                 \
            for (int i = 0; i < 4; ++i)                                       \
                a[i] = *(const bf16x8*)(pa + i * 16 * 96 + ks * 32);          \
            _Pragma("unroll")                                                 \
            for (int j = 0; j < 4; ++j)                                       \
                b[j] = *(const bf16x8*)(pb + j * 16 * 96 + ks * 32);          \
            __builtin_amdgcn_s_setprio(1);                                    \
            _Pragma("unroll")                                                 \
            for (int i = 0; i < 4; ++i)                                       \
                _Pragma("unroll")                                             \
                for (int j = 0; j < 4; ++j)                                   \
                    acc[i][j] = __builtin_amdgcn_mfma_f32_16x16x32_bf16(      \
                        a[i], b[j], acc[i][j], 0, 0, 0);                      \
            __builtin_amdgcn_s_setprio(0);                                    \
        }                                                                     \
    }

// QKV GEMM: N=3456 (Q|K|V). Q,K -> BF16; V -> VT bf16 [bh][d][t] directly.
__global__ __launch_bounds__(256)
void gemm_qkv_b(const __bf16* __restrict__ Ac, const __bf16* __restrict__ Bw,
                __bf16* __restrict__ Cq, __bf16* __restrict__ Ck,
                __bf16* __restrict__ VTout)
{
    const int bid = blockIdx.x;
    const int gid = (bid & 7) * 108 + (bid >> 3);   // 864 = 8 * 108
    const int n0  = (gid >> 5) * 128;
    const int m0  = (gid & 31) * 128;
    GEMM_PURE_CORE(Ac, Bw, n0, m0)

    const int seg = n0 / NP_;                 // block fully inside one segment
    const int rbase = m0 + wr + (lane >> 4) * 4;
    const int cbase = n0 - seg * NP_ + wc + (lane & 15);

    if (seg < 2) {
        __bf16* C = seg ? Ck : Cq;
        #pragma unroll
        for (int i = 0; i < 4; ++i)
            #pragma unroll
            for (int j = 0; j < 4; ++j) {
                const int n = cbase + j * 16;
                if (n < DIM_) {
                    #pragma unroll
                    for (int r = 0; r < 4; ++r)
                        C[(size_t)(rbase + i * 16 + r) * DIM_ + n] =
                            (__bf16)acc[i][j][r];
                }
            }
    } else {
        #pragma unroll
        for (int i = 0; i < 4; ++i) {
            const int tg = rbase + i * 16;            // mult of 4
            const int bb = tg >> 11, tt = tg & (T_ - 1);
            #pragma unroll
            for (int j = 0; j < 4; ++j) {
                const int n = cbase + j * 16;
                if (n < DIM_) {
                    const int h = n / 65, d = n - h * 65;
                    const size_t off =
                        ((size_t)(bb * H_ + h) * VTR_ + d) * T_ + tt;
                    uint2 pk;
                    pk.x = pack_bf16(acc[i][j][0], acc[i][j][1]);
                    pk.y = pack_bf16(acc[i][j][2], acc[i][j][3]);
                    *(uint2*)(VTout + off) = pk;
                }
            }
        }
    }
}

// OUT GEMM: plain bf16, K=1056. 288 blocks, XCD swizzle. out fp32.
__global__ __launch_bounds__(256)
void gemm_out_b(const __bf16* __restrict__ Ac, const __bf16* __restrict__ Bw,
                float* __restrict__ C)
{
    const int bid = blockIdx.x;
    const int gid = (bid & 7) * 36 + (bid >> 3);    // 288 = 8 * 36
    const int n0  = (gid >> 5) * 128;
    const int m0  = (gid & 31) * 128;
    GEMM_PURE_CORE(Ac, Bw, n0, m0)

    const int rbase = m0 + wr + (lane >> 4) * 4;
    const int cbase = n0 + wc + (lane & 15);
    #pragma unroll
    for (int i = 0; i < 4; ++i)
        #pragma unroll
        for (int j = 0; j < 4; ++j) {
            const int n = cbase + j * 16;
            if (n < DIM_) {
                #pragma unroll
                for (int r = 0; r < 4; ++r)
                    C[(size_t)(rbase + i * 16 + r) * DIM_ + n] = acc[i][j][r];
            }
        }
}

// ---------------------------------------------------------------------------
// Rotary + Lorentz-fold conversion (round-17-verified), bf16 input.
// XB[bh][t][96]:
//   Q side: cols 0..63 = SCALE*rot; col64,65 = -SCALE*c; col66 = -SCALE*a_hi.
//   K side: cols 0..63 = rot; col64 = b_hi, col65 = b_lo, col66 = b_hi.
// QK MFMA over 96 dims = SCALE*(spatial - q0k0) + per-row const (cancels).
// ---------------------------------------------------------------------------
__global__ __launch_bounds__(256)
void rotary2(const __bf16* __restrict__ Xq, const __bf16* __restrict__ Xk,
             __bf16* __restrict__ QB, __bf16* __restrict__ KB)
{
    const int gwid = (blockIdx.x * 256 + threadIdx.x) >> 6;  // 0..131071
    const int lane = threadIdx.x & 63;
    const int which = gwid >> 16;          // 0 = q, 1 = k
    const int wid   = gwid & 65535;

    const float SCALE = 0.18033688f;       // log2(e)/8

    const int h  = wid & (H_ - 1);
    const int bt = wid >> 4;               // b*T + t
    const int t  = bt & (T_ - 1);
    const int b  = bt >> 11;
    const __bf16* base = (which ? Xk : Xq) + (size_t)bt * DIM_ + h * HD1_;

    const int j = lane & 31;
    const float pw = powf(10000.0f, (float)j * (1.0f / 32.0f));
    const float fr = (float)t * (1.0f / pw);
    const float cs = cosf(fr);
    const float sn = sinf(fr);

    const float x1 = (float)base[1 + j];
    const float x2 = (float)base[33 + j];

    float rot = (lane < 32) ? (x1 * cs + x2 * sn)
                            : (x2 * cs - x1 * sn);
    rot = fminf(fmaxf(rot, -1000.0f), 1000.0f);

    float sq = rot * rot;
    #pragma unroll
    for (int off = 32; off >= 1; off >>= 1)
        sq += __shfl_xor(sq, off, 64);
    sq = fminf(fmaxf(sq, 0.0f), 1.0e6f);

    const float x0 = sqrtf((1.0f + sq) + 1.0e-6f);

    __bf16* XB = which ? KB : QB;
    const size_t base96 = (size_t)((b * H_ + h) * T_ + t) * QKW_;
    XB[base96 + lane] = which ? (__bf16)rot : (__bf16)(SCALE * rot);

    if (lane < 32) {
        float v = 0.0f;
        const float d0 = x0 - 5.25f;
        if (which) {                       // K side: b_hi, b_lo, b_hi
            const float bh = (float)(__bf16)d0;
            if (lane == 0 || lane == 2) v = bh;
            else if (lane == 1) v = d0 - bh;
        } else {                           // Q side: -S*c, -S*c, -S*a_hi
            if (lane < 2) v = -SCALE * 5.25f;
            else if (lane == 2) v = -SCALE * (float)(__bf16)d0;
        }
        XB[base96 + 64 + lane] = (__bf16)v;
    }
}

// ---------------------------------------------------------------------------
// MFMA attention v10: v9 numerics with QBLK=256 (4 q-tiles/block): each K/V
// staging + barrier pair amortized over 88 MFMA/wave.  Grid (bh=32, qblk=8)
// = 256 blocks = exactly 1/CU, fully resident.  LDS 70 KB (<80).  Q in regs
// (aq[4][3]).  Kt dbuf w/ rotation swizzle; single Vt; p=exp2(sc); ones-row
// denominator.  bid%8 = bh%8 (XCD locality).
// ---------------------------------------------------------------------------
__global__ __launch_bounds__(256)
void attn_mfma10(const __bf16* __restrict__ QB, const __bf16* __restrict__ KB,
                 const __bf16* __restrict__ VT, __bf16* __restrict__ yb)
{
    __shared__ __bf16 Kt[2][64 * 96] __attribute__((aligned(16)));
    __shared__ __bf16 Vt[80 * 64] __attribute__((aligned(16)));
    __shared__ __bf16 Pt[256 * 72] __attribute__((aligned(16)));

    const int tid  = threadIdx.x;
    const int lane = tid & 63;
    const int w    = tid >> 6;
    const int lx   = lane & 15;
    const int ly   = lane >> 4;
    const int bh   = blockIdx.x;           // XCD-local: bid%8 == bh%8
    const int q0r  = blockIdx.y * 256;

    const __bf16* QBb = QB + (size_t)bh * T_ * QKW_;
    const __bf16* KBb = KB + (size_t)bh * T_ * QKW_;
    const __bf16* VTb = VT + (size_t)bh * VTR_ * T_;

    // Q fragments: registers, read once (4 tiles x 96 dims)
    bf16x8 aq[4][3];
    #pragma unroll
    for (int t = 0; t < 4; ++t)
        #pragma unroll
        for (int ks = 0; ks < 3; ++ks)
            aq[t][ks] = *(const bf16x8*)
                (QBb + (size_t)(q0r + t * 64 + w * 16 + lx) * QKW_ +
                 ks * 32 + ly * 8);

    ((unsigned*)Vt)[2304 + tid] = 0u;      // rows 72..79 (never re-written)

    // K staging offsets: 768 chunks; inverse rotation swizzle on SOURCE
    int offk[3];
    #pragma unroll
    for (int qi = 0; qi < 3; ++qi) {
        const int cid = qi * 256 + tid;
        const int s = cid / 12, p = cid - s * 12;
        const int c = (p & 12) | ((p - (s >> 1)) & 3);
        offk[qi] = s * QKW_ + c * 8;       // + s0*QKW_
    }
    int offv[3];
    #pragma unroll
    for (int qi = 0; qi < 3; ++qi) {
        const int cid = qi * 256 + tid;
        const int d = cid >> 3, jj = cid & 7;
        offv[qi] = d * T_ + (jj ^ (d & 7)) * 8;   // + s0
    }

    // prologue: stage K[0]
    #pragma unroll
    for (int qi = 0; qi < 3; ++qi)
        gload_lds16(KBb + offk[qi], &Kt[0][(qi * 256 + tid) * 8]);

    f32x4 acc_o[4][5];
    #pragma unroll
    for (int t = 0; t < 4; ++t)
        #pragma unroll
        for (int n = 0; n < 5; ++n) acc_o[t][n] = (f32x4){0.f, 0.f, 0.f, 0.f};

    const int rr = (ly + (lx >> 1)) & 3;   // Kt frag-read rotation

    int cur = 0;
    for (int it = 0; it < T_ / 64; ++it) {
        const int s0 = it * 64;
        __syncthreads();   // barrier1: Kt[cur] staged; prev PV done with Vt

        // stage V[it] (drains at barrier2)
        gload_lds16(VTb + s0 + offv[0], Vt + tid * 8);
        gload_lds16(VTb + s0 + offv[1], Vt + (256 + tid) * 8);
        if (tid < 64)
            gload_lds16(VTb + s0 + offv[2], Vt + (512 + tid) * 8);

        if (it + 1 < T_ / 64) {            // prefetch K[it+1] into Kt[cur^1]
            const size_t koff = (size_t)(s0 + 64) * QKW_;
            #pragma unroll
            for (int qi = 0; qi < 3; ++qi)
                gload_lds16(KBb + koff + offk[qi],
                            &Kt[cur ^ 1][(qi * 256 + tid) * 8]);
        }

        // ---- QK^T + exp2 + Pt write, all 4 q-tiles ----
        #pragma unroll
        for (int t = 0; t < 4; ++t) {
            f32x4 sc[4];
            __builtin_amdgcn_s_setprio(1);
            #pragma unroll
            for (int n = 0; n < 4; ++n) {
                f32x4 c = (f32x4){0.f, 0.f, 0.f, 0.f};
                #pragma unroll
                for (int ks = 0; ks < 3; ++ks) {
                    const bf16x8 bk = *(const bf16x8*)
                        &Kt[cur][(n * 16 + lx) * 96 + ks * 32 + rr * 8];
                    c = __builtin_amdgcn_mfma_f32_16x16x32_bf16(
                        aq[t][ks], bk, c, 0, 0, 0);
                }
                sc[n] = c;
            }
            __builtin_amdgcn_s_setprio(0);

            #pragma unroll
            for (int n = 0; n < 4; ++n)
                #pragma unroll
                for (int r = 0; r < 4; ++r)
                    Pt[(t * 64 + w * 16 + ly * 4 + r) * 72 + n * 16 + lx] =
                        (__bf16)exp2_fast(sc[n][r]);
        }

        __syncthreads();   // barrier2: V[it] staged (vmcnt drained)

        // ---- PV, all 4 q-tiles (n=4 covers d=64..79: d=65 ones-row) ----
        #pragma unroll
        for (int t = 0; t < 4; ++t) {
            bf16x8 ap[2];
            #pragma unroll
            for (int ks = 0; ks < 2; ++ks)
                ap[ks] = *(const bf16x8*)
                    &Pt[(t * 64 + w * 16 + lx) * 72 + ks * 32 + ly * 8];
            __builtin_amdgcn_s_setprio(1);
            #pragma unroll
            for (int n = 0; n < 5; ++n) {
                f32x4 c = acc_o[t][n];
                #pragma unroll
                for (int ks = 0; ks < 2; ++ks) {
                    const bf16x8 bv = *(const bf16x8*)
                        &Vt[(n * 16 + lx) * 64 +
                            ((ks * 4 + ly) ^ (lx & 7)) * 8];
                    c = __builtin_amdgcn_mfma_f32_16x16x32_bf16(
                        ap[ks], bv, c, 0, 0, 0);
                }
                acc_o[t][n] = c;
            }
            __builtin_amdgcn_s_setprio(0);
        }
        cur ^= 1;
    }

    // ---- epilogue: l in acc_o[t][4][r] of lane lx==1; write yb bf16 ----
    const int b = bh >> 4, h = bh & 15;
    #pragma unroll
    for (int t = 0; t < 4; ++t)
        #pragma unroll
        for (int r = 0; r < 4; ++r) {
            const float l = __shfl(acc_o[t][4][r], (lane & 48) + 1, 64);
            const float inv = 1.0f / l;
            const int qrow = q0r + t * 64 + w * 16 + ly * 4 + r;
            __bf16* yrow = yb + (size_t)(b * T_ + qrow) * KP_ + h * HD1_;
            #pragma unroll
            for (int n = 0; n < 4; ++n)
                yrow[n * 16 + lx] = (__bf16)(acc_o[t][n][r] * inv);
            if (lx == 0) yrow[64] = (__bf16)(acc_o[t][4][r] * inv);
        }
}

// ---------------------------------------------------------------------------
// Workspace (~70 MB flat, <= 91.4 MB proven):
//  qb bf16 [4096][1040] | kb bf16 | xb bf16 (-> yb) | Wb3 | QB[.][96] |
//  KB[.][96] | VT | WpB
// ---------------------------------------------------------------------------
extern "C" void kernel_launch(void* const* d_in, const int* in_sizes, int n_in,
                              void* d_out, int out_size, void* d_ws, size_t ws_size,
                              hipStream_t stream)
{
    const float* x  = (const float*)d_in[0];
    const float* Wq = (const float*)d_in[1];
    const float* Wk = (const float*)d_in[2];
    const float* Wv = (const float*)d_in[3];
    const float* Wp = (const float*)d_in[4];

    __bf16* qb  = (__bf16*)d_ws;                       // [4096][1040]
    __bf16* kb  = qb + (size_t)MROWS_ * DIM_;          // [4096][1040]
    __bf16* xb  = kb + (size_t)MROWS_ * DIM_;          // [4096][1056], -> yb
    __bf16* Wb3 = xb + (size_t)MROWS_ * KP_;           // [3456][1056]
    __bf16* QB  = Wb3 + (size_t)NP3_ * KP_;            // [32][2048][96]
    __bf16* KB  = QB + (size_t)NBH_ * T_ * QKW_;       // [32][2048][96]
    __bf16* VT  = KB + (size_t)NBH_ * T_ * QKW_;       // [32][72][2048]
    __bf16* WpB = VT + (size_t)NBH_ * VTR_ * T_;       // [1152][1056]
    __bf16* yb  = xb;                                  // overlay

    float* out = (float*)d_out;

    dim3 blk(256);

    prep_all<<<dim3(PR_D_ / 256), blk, 0, stream>>>(
        x, Wq, Wk, Wv, Wp, xb, Wb3, VT, WpB);
    gemm_qkv_b<<<dim3(864), blk, 0, stream>>>(xb, Wb3, qb, kb, VT);

    rotary2<<<dim3(2 * (B_ * T_ * H_) / 4), blk, 0, stream>>>(qb, kb, QB, KB);

    attn_mfma10<<<dim3(NBH_, T_ / 256), blk, 0, stream>>>(QB, KB, VT, yb);

    gemm_out_b<<<dim3(288), blk, 0, stream>>>(yb, WpB, out);
}

// Round 22
// 210.539 us; speedup vs baseline: 1.1470x; 1.1470x over previous
//
#include <hip/hip_runtime.h>
#include <math.h>

#define B_   2
#define T_   2048
#define DIM_ 1040
#define H_   16
#define HD_  64
#define HD1_ 65
#define NELEM (B_*T_*DIM_)

#define KP_   1056           // GEMM K padded (1040 -> 1056 = 11*96)
#define NP_   1152           // weight rows padded to mult of 128
#define NP3_  3456           // 3*NP_ : fused QKV weight rows
#define SEGS_ 132            // KP_/8
#define MROWS_ (B_*T_)       // 4096

#define NBH_  (B_*H_)        // 32
#define VTR_  72             // VT rows per bh (65 real + row65=ones + zeros)
#define QKW_  96             // QB/KB row width: 64 spatial + 3 Lorentz + pad

// prep_all fused ranges
#define PR_A_ (NP3_*SEGS_)                 // Wb3:   456192
#define PR_B_ (PR_A_ + MROWS_*SEGS_)       // xb:    996864
#define PR_C_ (PR_B_ + NBH_*7*256)         // VT tail: 1054208
#define PR_D_ (PR_C_ + NP_*SEGS_)          // WpB:  1206272

typedef __attribute__((ext_vector_type(8))) __bf16 bf16x8;
typedef __attribute__((ext_vector_type(4))) float f32x4;
typedef __attribute__((ext_vector_type(8))) unsigned short ushort8;

static __device__ __forceinline__ unsigned pack_bf16(float lo, float hi) {
    __bf16 a = (__bf16)lo, c = (__bf16)hi;
    unsigned short ua, uc;
    __builtin_memcpy(&ua, &a, 2);
    __builtin_memcpy(&uc, &c, 2);
    return ((unsigned)uc << 16) | ua;
}

static __device__ __forceinline__ float exp2_fast(float x) {
    float r;
    asm("v_exp_f32 %0, %1" : "=v"(r) : "v"(x));
    return r;
}

// ---------------------------------------------------------------------------
// Plain-bf16 row converter: rows/cols padded with zeros.
// ---------------------------------------------------------------------------
static __device__ __forceinline__ void conv_row_plain(
    const float* __restrict__ in, __bf16* __restrict__ out, int r, int s,
    int rows_in)
{
    float v[8];
    if (r < rows_in && s < 130) {           // 130*8 = 1040 exactly
        const float4 f0 = *(const float4*)(in + (size_t)r * DIM_ + s * 8);
        const float4 f1 = *(const float4*)(in + (size_t)r * DIM_ + s * 8 + 4);
        v[0]=f0.x; v[1]=f0.y; v[2]=f0.z; v[3]=f0.w;
        v[4]=f1.x; v[5]=f1.y; v[6]=f1.z; v[7]=f1.w;
    } else {
        #pragma unroll
        for (int i = 0; i < 8; ++i) v[i] = 0.0f;
    }
    __bf16 t[8] __attribute__((aligned(16)));
    #pragma unroll
    for (int i = 0; i < 8; ++i) t[i] = (__bf16)v[i];
    *(ushort8*)(out) = *(const ushort8*)(t);
}

// ---------------------------------------------------------------------------
// Fused prep: Wq|Wk|Wv -> Wb3, x -> xb, VT tail rows (row65 = ones for the
// free softmax denominator), Wp -> WpB.  All plain bf16, one launch.
// xb doubles as yb later; zero cols 1040..1055 survive attn.
// ---------------------------------------------------------------------------
__global__ __launch_bounds__(256)
void prep_all(const float* __restrict__ x,  const float* __restrict__ Wq,
              const float* __restrict__ Wk, const float* __restrict__ Wv,
              const float* __restrict__ Wp, __bf16* __restrict__ xb,
              __bf16* __restrict__ Wb3, __bf16* __restrict__ VT,
              __bf16* __restrict__ WpB)
{
    const int gid = blockIdx.x * 256 + threadIdx.x;
    if (gid < PR_A_) {
        const int r = gid / SEGS_, s = gid - r * SEGS_;
        const int seg = r / NP_, rr = r - seg * NP_;
        const float* in = (seg == 0) ? Wq : (seg == 1) ? Wk : Wv;
        conv_row_plain(in, Wb3 + (size_t)r * KP_ + s * 8, rr, s, DIM_);
    } else if (gid < PR_B_) {
        const int g = gid - PR_A_;
        const int r = g / SEGS_, s = g - r * SEGS_;
        conv_row_plain(x, xb + (size_t)r * KP_ + s * 8, r, s, MROWS_);
    } else if (gid < PR_C_) {
        const int cid = gid - PR_B_;
        const int bh  = cid / 1792;
        const int rem = cid - bh * 1792;
        const int row = 65 + rem / 256;
        const int tc  = rem - (row - 65) * 256;
        const unsigned val = (row == 65) ? 0x3F803F80u : 0u;
        unsigned* p = (unsigned*)(VT + ((size_t)bh * VTR_ + row) * T_ + tc * 8);
        p[0] = val; p[1] = val; p[2] = val; p[3] = val;
    } else {
        const int g = gid - PR_C_;
        const int r = g / SEGS_, s = g - r * SEGS_;
        conv_row_plain(Wp, WpB + (size_t)r * KP_ + s * 8, r, s, DIM_);
    }
}

// ---------------------------------------------------------------------------
// global->LDS async 16B
// ---------------------------------------------------------------------------
__device__ __forceinline__ void gload_lds16(const void* g, void* l) {
    __builtin_amdgcn_global_load_lds(
        (const __attribute__((address_space(1))) void*)g,
        (__attribute__((address_space(3))) void*)l, 16, 0, 0);
}

// ---------------------------------------------------------------------------
// PURE GEMM core (both operands pre-converted bf16, row stride KP_):
// barrier / 12x global_load_lds / barrier / 48 MFMA per 96-wide K-step.
// ---------------------------------------------------------------------------
#define GEMM_PURE_CORE(Ac_, Bw_, N0_, M0_)                                    \
    __shared__ __bf16 As[128 * 96];                                           \
    __shared__ __bf16 Bs[128 * 96];                                           \
    const int tid  = threadIdx.x;                                             \
    const int lane = tid & 63;                                                \
    const int w    = tid >> 6;                                                \
    const int wr   = (w >> 1) * 64, wc = (w & 1) * 64;                        \
    const __bf16* gap[6]; const __bf16* gb[6];                                \
    _Pragma("unroll")                                                         \
    for (int qi = 0; qi < 6; ++qi) {                                          \
        const int cid = qi * 256 + tid;                                       \
        const int rr  = cid / 12, cc = cid - rr * 12;                         \
        gap[qi] = Ac_ + (size_t)(M0_ + rr) * KP_ + cc * 8;                    \
        gb[qi]  = Bw_ + (size_t)(N0_ + rr) * KP_ + cc * 8;                    \
    }                                                                         \
    f32x4 acc[4][4];                                                          \
    _Pragma("unroll")                                                         \
    for (int i = 0; i < 4; ++i)                                               \
        _Pragma("unroll")                                                     \
        for (int j = 0; j < 4; ++j) acc[i][j] = (f32x4){0.f, 0.f, 0.f, 0.f};  \
    const __bf16* pa = As + (wr + (lane & 15)) * 96 + (lane >> 4) * 8;        \
    const __bf16* pb = Bs + (wc + (lane & 15)) * 96 + (lane >> 4) * 8;        \
    for (int k0 = 0; k0 < KP_; k0 += 96) {                                    \
        __syncthreads();                                                      \
        _Pragma("unroll")                                                     \
        for (int qi = 0; qi < 6; ++qi) {                                      \
            gload_lds16(gap[qi] + k0, As + (qi * 256 + tid) * 8);             \
            gload_lds16(gb[qi]  + k0, Bs + (qi * 256 + tid) * 8);             \
        }                                                                     \
        __syncthreads();                                                      \
        _Pragma("unroll")                                                     \
        for (int ks = 0; ks < 3; ++ks) {                                      \
            bf16x8 a[4], b[4];                                                \
            _Pragma("unroll")                                                 \
            for (int i = 0; i < 4; ++i)                                       \
                a[i] = *(const bf16x8*)(pa + i * 16 * 96 + ks * 32);          \
            _Pragma("unroll")                                                 \
            for (int j = 0; j < 4; ++j)                                       \
                b[j] = *(const bf16x8*)(pb + j * 16 * 96 + ks * 32);          \
            __builtin_amdgcn_s_setprio(1);                                    \
            _Pragma("unroll")                                                 \
            for (int i = 0; i < 4; ++i)                                       \
                _Pragma("unroll")                                             \
                for (int j = 0; j < 4; ++j)                                   \
                    acc[i][j] = __builtin_amdgcn_mfma_f32_16x16x32_bf16(      \
                        a[i], b[j], acc[i][j], 0, 0, 0);                      \
            __builtin_amdgcn_s_setprio(0);                                    \
        }                                                                     \
    }

// QKV GEMM: N=3456 (Q|K|V). Q,K -> BF16; V -> VT bf16 [bh][d][t] directly.
__global__ __launch_bounds__(256)
void gemm_qkv_b(const __bf16* __restrict__ Ac, const __bf16* __restrict__ Bw,
                __bf16* __restrict__ Cq, __bf16* __restrict__ Ck,
                __bf16* __restrict__ VTout)
{
    const int bid = blockIdx.x;
    const int gid = (bid & 7) * 108 + (bid >> 3);   // 864 = 8 * 108
    const int n0  = (gid >> 5) * 128;
    const int m0  = (gid & 31) * 128;
    GEMM_PURE_CORE(Ac, Bw, n0, m0)

    const int seg = n0 / NP_;                 // block fully inside one segment
    const int rbase = m0 + wr + (lane >> 4) * 4;
    const int cbase = n0 - seg * NP_ + wc + (lane & 15);

    if (seg < 2) {
        __bf16* C = seg ? Ck : Cq;
        #pragma unroll
        for (int i = 0; i < 4; ++i)
            #pragma unroll
            for (int j = 0; j < 4; ++j) {
                const int n = cbase + j * 16;
                if (n < DIM_) {
                    #pragma unroll
                    for (int r = 0; r < 4; ++r)
                        C[(size_t)(rbase + i * 16 + r) * DIM_ + n] =
                            (__bf16)acc[i][j][r];
                }
            }
    } else {
        #pragma unroll
        for (int i = 0; i < 4; ++i) {
            const int tg = rbase + i * 16;            // mult of 4
            const int bb = tg >> 11, tt = tg & (T_ - 1);
            #pragma unroll
            for (int j = 0; j < 4; ++j) {
                const int n = cbase + j * 16;
                if (n < DIM_) {
                    const int h = n / 65, d = n - h * 65;
                    const size_t off =
                        ((size_t)(bb * H_ + h) * VTR_ + d) * T_ + tt;
                    uint2 pk;
                    pk.x = pack_bf16(acc[i][j][0], acc[i][j][1]);
                    pk.y = pack_bf16(acc[i][j][2], acc[i][j][3]);
                    *(uint2*)(VTout + off) = pk;
                }
            }
        }
    }
}

// OUT GEMM: plain bf16, K=1056. 288 blocks, XCD swizzle. out fp32.
__global__ __launch_bounds__(256)
void gemm_out_b(const __bf16* __restrict__ Ac, const __bf16* __restrict__ Bw,
                float* __restrict__ C)
{
    const int bid = blockIdx.x;
    const int gid = (bid & 7) * 36 + (bid >> 3);    // 288 = 8 * 36
    const int n0  = (gid >> 5) * 128;
    const int m0  = (gid & 31) * 128;
    GEMM_PURE_CORE(Ac, Bw, n0, m0)

    const int rbase = m0 + wr + (lane >> 4) * 4;
    const int cbase = n0 + wc + (lane & 15);
    #pragma unroll
    for (int i = 0; i < 4; ++i)
        #pragma unroll
        for (int j = 0; j < 4; ++j) {
            const int n = cbase + j * 16;
            if (n < DIM_) {
                #pragma unroll
                for (int r = 0; r < 4; ++r)
                    C[(size_t)(rbase + i * 16 + r) * DIM_ + n] = acc[i][j][r];
            }
        }
}

// ---------------------------------------------------------------------------
// Rotary + Lorentz-fold conversion (round-17-verified), bf16 input.
// XB[bh][t][96]:
//   Q side: cols 0..63 = SCALE*rot; col64,65 = -SCALE*c; col66 = -SCALE*a_hi.
//   K side: cols 0..63 = rot; col64 = b_hi, col65 = b_lo, col66 = b_hi.
// QK MFMA over 96 dims = SCALE*(spatial - q0k0) + per-row const (cancels).
// ---------------------------------------------------------------------------
__global__ __launch_bounds__(256)
void rotary2(const __bf16* __restrict__ Xq, const __bf16* __restrict__ Xk,
             __bf16* __restrict__ QB, __bf16* __restrict__ KB)
{
    const int gwid = (blockIdx.x * 256 + threadIdx.x) >> 6;  // 0..131071
    const int lane = threadIdx.x & 63;
    const int which = gwid >> 16;          // 0 = q, 1 = k
    const int wid   = gwid & 65535;

    const float SCALE = 0.18033688f;       // log2(e)/8

    const int h  = wid & (H_ - 1);
    const int bt = wid >> 4;               // b*T + t
    const int t  = bt & (T_ - 1);
    const int b  = bt >> 11;
    const __bf16* base = (which ? Xk : Xq) + (size_t)bt * DIM_ + h * HD1_;

    const int j = lane & 31;
    const float pw = powf(10000.0f, (float)j * (1.0f / 32.0f));
    const float fr = (float)t * (1.0f / pw);
    const float cs = cosf(fr);
    const float sn = sinf(fr);

    const float x1 = (float)base[1 + j];
    const float x2 = (float)base[33 + j];

    float rot = (lane < 32) ? (x1 * cs + x2 * sn)
                            : (x2 * cs - x1 * sn);
    rot = fminf(fmaxf(rot, -1000.0f), 1000.0f);

    float sq = rot * rot;
    #pragma unroll
    for (int off = 32; off >= 1; off >>= 1)
        sq += __shfl_xor(sq, off, 64);
    sq = fminf(fmaxf(sq, 0.0f), 1.0e6f);

    const float x0 = sqrtf((1.0f + sq) + 1.0e-6f);

    __bf16* XB = which ? KB : QB;
    const size_t base96 = (size_t)((b * H_ + h) * T_ + t) * QKW_;
    XB[base96 + lane] = which ? (__bf16)rot : (__bf16)(SCALE * rot);

    if (lane < 32) {
        float v = 0.0f;
        const float d0 = x0 - 5.25f;
        if (which) {                       // K side: b_hi, b_lo, b_hi
            const float bh = (float)(__bf16)d0;
            if (lane == 0 || lane == 2) v = bh;
            else if (lane == 1) v = d0 - bh;
        } else {                           // Q side: -S*c, -S*c, -S*a_hi
            if (lane < 2) v = -SCALE * 5.25f;
            else if (lane == 2) v = -SCALE * (float)(__bf16)d0;
        }
        XB[base96 + 64 + lane] = (__bf16)v;
    }
}

// ---------------------------------------------------------------------------
// MFMA attention v9 (round-20-verified optimum): Lorentz-folded 96-dim QK,
// p=exp2(sc), ones-row denominator, Q in regs, Kt dbuf w/ rotation swizzle,
// single Vt; QBLK=128 (2 q-tiles/block, 44 MFMA/wave/tile).  Grid
// (bh=32, qblk=16) = 512 blocks = 2/CU resident (the measured sweet spot:
// 1q/4blk=94us, 2q/2blk=77us, 4q/1blk=107us).  LDS 52 KB.  bid%8 = bh%8.
// ---------------------------------------------------------------------------
__global__ __launch_bounds__(256)
void attn_mfma9(const __bf16* __restrict__ QB, const __bf16* __restrict__ KB,
                const __bf16* __restrict__ VT, __bf16* __restrict__ yb)
{
    __shared__ __bf16 Kt[2][64 * 96] __attribute__((aligned(16)));
    __shared__ __bf16 Vt[80 * 64] __attribute__((aligned(16)));
    __shared__ __bf16 Pt[128 * 72] __attribute__((aligned(16)));

    const int tid  = threadIdx.x;
    const int lane = tid & 63;
    const int w    = tid >> 6;
    const int lx   = lane & 15;
    const int ly   = lane >> 4;
    const int bh   = blockIdx.x;           // XCD-local: bid%8 == bh%8
    const int q0r  = blockIdx.y * 128;

    const __bf16* QBb = QB + (size_t)bh * T_ * QKW_;
    const __bf16* KBb = KB + (size_t)bh * T_ * QKW_;
    const __bf16* VTb = VT + (size_t)bh * VTR_ * T_;

    // Q fragments: registers, read once (2 tiles x 96 dims)
    bf16x8 aq[2][3];
    #pragma unroll
    for (int t = 0; t < 2; ++t)
        #pragma unroll
        for (int ks = 0; ks < 3; ++ks)
            aq[t][ks] = *(const bf16x8*)
                (QBb + (size_t)(q0r + t * 64 + w * 16 + lx) * QKW_ +
                 ks * 32 + ly * 8);

    ((unsigned*)Vt)[2304 + tid] = 0u;      // rows 72..79 (never re-written)

    // K staging offsets: 768 chunks; inverse rotation swizzle on SOURCE
    int offk[3];
    #pragma unroll
    for (int qi = 0; qi < 3; ++qi) {
        const int cid = qi * 256 + tid;
        const int s = cid / 12, p = cid - s * 12;
        const int c = (p & 12) | ((p - (s >> 1)) & 3);
        offk[qi] = s * QKW_ + c * 8;       // + s0*QKW_
    }
    int offv[3];
    #pragma unroll
    for (int qi = 0; qi < 3; ++qi) {
        const int cid = qi * 256 + tid;
        const int d = cid >> 3, jj = cid & 7;
        offv[qi] = d * T_ + (jj ^ (d & 7)) * 8;   // + s0
    }

    // prologue: stage K[0]
    #pragma unroll
    for (int qi = 0; qi < 3; ++qi)
        gload_lds16(KBb + offk[qi], &Kt[0][(qi * 256 + tid) * 8]);

    f32x4 acc_o[2][5];
    #pragma unroll
    for (int t = 0; t < 2; ++t)
        #pragma unroll
        for (int n = 0; n < 5; ++n) acc_o[t][n] = (f32x4){0.f, 0.f, 0.f, 0.f};

    const int rr = (ly + (lx >> 1)) & 3;   // Kt frag-read rotation

    int cur = 0;
    for (int it = 0; it < T_ / 64; ++it) {
        const int s0 = it * 64;
        __syncthreads();   // barrier1: Kt[cur] staged; prev PV done with Vt

        // stage V[it] (drains at barrier2)
        gload_lds16(VTb + s0 + offv[0], Vt + tid * 8);
        gload_lds16(VTb + s0 + offv[1], Vt + (256 + tid) * 8);
        if (tid < 64)
            gload_lds16(VTb + s0 + offv[2], Vt + (512 + tid) * 8);

        if (it + 1 < T_ / 64) {            // prefetch K[it+1] into Kt[cur^1]
            const size_t koff = (size_t)(s0 + 64) * QKW_;
            #pragma unroll
            for (int qi = 0; qi < 3; ++qi)
                gload_lds16(KBb + koff + offk[qi],
                            &Kt[cur ^ 1][(qi * 256 + tid) * 8]);
        }

        // ---- QK^T + exp2 + Pt write, both q-tiles ----
        #pragma unroll
        for (int t = 0; t < 2; ++t) {
            f32x4 sc[4];
            __builtin_amdgcn_s_setprio(1);
            #pragma unroll
            for (int n = 0; n < 4; ++n) {
                f32x4 c = (f32x4){0.f, 0.f, 0.f, 0.f};
                #pragma unroll
                for (int ks = 0; ks < 3; ++ks) {
                    const bf16x8 bk = *(const bf16x8*)
                        &Kt[cur][(n * 16 + lx) * 96 + ks * 32 + rr * 8];
                    c = __builtin_amdgcn_mfma_f32_16x16x32_bf16(
                        aq[t][ks], bk, c, 0, 0, 0);
                }
                sc[n] = c;
            }
            __builtin_amdgcn_s_setprio(0);

            #pragma unroll
            for (int n = 0; n < 4; ++n)
                #pragma unroll
                for (int r = 0; r < 4; ++r)
                    Pt[(t * 64 + w * 16 + ly * 4 + r) * 72 + n * 16 + lx] =
                        (__bf16)exp2_fast(sc[n][r]);
        }

        __syncthreads();   // barrier2: V[it] staged (vmcnt drained)

        // ---- PV, both q-tiles (n=4 covers d=64..79: d=65 ones-row -> l) ----
        #pragma unroll
        for (int t = 0; t < 2; ++t) {
            bf16x8 ap[2];
            #pragma unroll
            for (int ks = 0; ks < 2; ++ks)
                ap[ks] = *(const bf16x8*)
                    &Pt[(t * 64 + w * 16 + lx) * 72 + ks * 32 + ly * 8];
            __builtin_amdgcn_s_setprio(1);
            #pragma unroll
            for (int n = 0; n < 5; ++n) {
                f32x4 c = acc_o[t][n];
                #pragma unroll
                for (int ks = 0; ks < 2; ++ks) {
                    const bf16x8 bv = *(const bf16x8*)
                        &Vt[(n * 16 + lx) * 64 +
                            ((ks * 4 + ly) ^ (lx & 7)) * 8];
                    c = __builtin_amdgcn_mfma_f32_16x16x32_bf16(
                        ap[ks], bv, c, 0, 0, 0);
                }
                acc_o[t][n] = c;
            }
            __builtin_amdgcn_s_setprio(0);
        }
        cur ^= 1;
    }

    // ---- epilogue: l in acc_o[t][4][r] of lane lx==1; write yb bf16 ----
    const int b = bh >> 4, h = bh & 15;
    #pragma unroll
    for (int t = 0; t < 2; ++t)
        #pragma unroll
        for (int r = 0; r < 4; ++r) {
            const float l = __shfl(acc_o[t][4][r], (lane & 48) + 1, 64);
            const float inv = 1.0f / l;
            const int qrow = q0r + t * 64 + w * 16 + ly * 4 + r;
            __bf16* yrow = yb + (size_t)(b * T_ + qrow) * KP_ + h * HD1_;
            #pragma unroll
            for (int n = 0; n < 4; ++n)
                yrow[n * 16 + lx] = (__bf16)(acc_o[t][n][r] * inv);
            if (lx == 0) yrow[64] = (__bf16)(acc_o[t][4][r] * inv);
        }
}

// ---------------------------------------------------------------------------
// Workspace (~70 MB flat, <= 91.4 MB proven):
//  qb bf16 [4096][1040] | kb bf16 | xb bf16 (-> yb) | Wb3 | QB[.][96] |
//  KB[.][96] | VT | WpB
// ---------------------------------------------------------------------------
extern "C" void kernel_launch(void* const* d_in, const int* in_sizes, int n_in,
                              void* d_out, int out_size, void* d_ws, size_t ws_size,
                              hipStream_t stream)
{
    const float* x  = (const float*)d_in[0];
    const float* Wq = (const float*)d_in[1];
    const float* Wk = (const float*)d_in[2];
    const float* Wv = (const float*)d_in[3];
    const float* Wp = (const float*)d_in[4];

    __bf16* qb  = (__bf16*)d_ws;                       // [4096][1040]
    __bf16* kb  = qb + (size_t)MROWS_ * DIM_;          // [4096][1040]
    __bf16* xb  = kb + (size_t)MROWS_ * DIM_;          // [4096][1056], -> yb
    __bf16* Wb3 = xb + (size_t)MROWS_ * KP_;           // [3456][1056]
    __bf16* QB  = Wb3 + (size_t)NP3_ * KP_;            // [32][2048][96]
    __bf16* KB  = QB + (size_t)NBH_ * T_ * QKW_;       // [32][2048][96]
    __bf16* VT  = KB + (size_t)NBH_ * T_ * QKW_;       // [32][72][2048]
    __bf16* WpB = VT + (size_t)NBH_ * VTR_ * T_;       // [1152][1056]
    __bf16* yb  = xb;                                  // overlay

    float* out = (float*)d_out;

    dim3 blk(256);

    prep_all<<<dim3(PR_D_ / 256), blk, 0, stream>>>(
        x, Wq, Wk, Wv, Wp, xb, Wb3, VT, WpB);
    gemm_qkv_b<<<dim3(864), blk, 0, stream>>>(xb, Wb3, qb, kb, VT);

    rotary2<<<dim3(2 * (B_ * T_ * H_) / 4), blk, 0, stream>>>(qb, kb, QB, KB);

    attn_mfma9<<<dim3(NBH_, T_ / 128), blk, 0, stream>>>(QB, KB, VT, yb);

    gemm_out_b<<<dim3(288), blk, 0, stream>>>(yb, WpB, out);
}

// Round 23
// 204.276 us; speedup vs baseline: 1.1822x; 1.0307x over previous
//
#include <hip/hip_runtime.h>
#include <math.h>

#define B_   2
#define T_   2048
#define DIM_ 1040
#define H_   16
#define HD_  64
#define HD1_ 65
#define NELEM (B_*T_*DIM_)

#define KP_   1056           // GEMM K padded (1040 -> 1056 = 11*96)
#define NP_   1152           // weight rows padded to mult of 128
#define NP3_  3456           // 3*NP_ : fused QKV weight rows
#define SEGS_ 132            // KP_/8
#define MROWS_ (B_*T_)       // 4096

#define NBH_  (B_*H_)        // 32
#define VTR_  72             // VT rows per bh (65 real + row65=ones + zeros)
#define QKW_  96             // QB/KB row width: 64 spatial + 3 Lorentz + pad

// prep_all fused ranges
#define PR_A_ (NP3_*SEGS_)                 // Wb3:   456192
#define PR_B_ (PR_A_ + MROWS_*SEGS_)       // xb:    996864
#define PR_C_ (PR_B_ + NBH_*7*256)         // VT tail: 1054208
#define PR_D_ (PR_C_ + NP_*SEGS_)          // WpB:  1206272

typedef __attribute__((ext_vector_type(8))) __bf16 bf16x8;
typedef __attribute__((ext_vector_type(4))) float f32x4;
typedef __attribute__((ext_vector_type(8))) unsigned short ushort8;

static __device__ __forceinline__ unsigned pack_bf16(float lo, float hi) {
    __bf16 a = (__bf16)lo, c = (__bf16)hi;
    unsigned short ua, uc;
    __builtin_memcpy(&ua, &a, 2);
    __builtin_memcpy(&uc, &c, 2);
    return ((unsigned)uc << 16) | ua;
}

static __device__ __forceinline__ float exp2_fast(float x) {
    float r;
    asm("v_exp_f32 %0, %1" : "=v"(r) : "v"(x));
    return r;
}

// ---------------------------------------------------------------------------
// Plain-bf16 row converter: rows/cols padded with zeros.
// ---------------------------------------------------------------------------
static __device__ __forceinline__ void conv_row_plain(
    const float* __restrict__ in, __bf16* __restrict__ out, int r, int s,
    int rows_in)
{
    float v[8];
    if (r < rows_in && s < 130) {           // 130*8 = 1040 exactly
        const float4 f0 = *(const float4*)(in + (size_t)r * DIM_ + s * 8);
        const float4 f1 = *(const float4*)(in + (size_t)r * DIM_ + s * 8 + 4);
        v[0]=f0.x; v[1]=f0.y; v[2]=f0.z; v[3]=f0.w;
        v[4]=f1.x; v[5]=f1.y; v[6]=f1.z; v[7]=f1.w;
    } else {
        #pragma unroll
        for (int i = 0; i < 8; ++i) v[i] = 0.0f;
    }
    __bf16 t[8] __attribute__((aligned(16)));
    #pragma unroll
    for (int i = 0; i < 8; ++i) t[i] = (__bf16)v[i];
    *(ushort8*)(out) = *(const ushort8*)(t);
}

// ---------------------------------------------------------------------------
// Fused prep: Wq|Wk|Wv -> Wb3, x -> xb, VT tail rows (row65 = ones for the
// free softmax denominator), Wp -> WpB.  All plain bf16, one launch.
// xb doubles as yb later; zero cols 1040..1055 survive attn.
// ---------------------------------------------------------------------------
__global__ __launch_bounds__(256)
void prep_all(const float* __restrict__ x,  const float* __restrict__ Wq,
              const float* __restrict__ Wk, const float* __restrict__ Wv,
              const float* __restrict__ Wp, __bf16* __restrict__ xb,
              __bf16* __restrict__ Wb3, __bf16* __restrict__ VT,
              __bf16* __restrict__ WpB)
{
    const int gid = blockIdx.x * 256 + threadIdx.x;
    if (gid < PR_A_) {
        const int r = gid / SEGS_, s = gid - r * SEGS_;
        const int seg = r / NP_, rr = r - seg * NP_;
        const float* in = (seg == 0) ? Wq : (seg == 1) ? Wk : Wv;
        conv_row_plain(in, Wb3 + (size_t)r * KP_ + s * 8, rr, s, DIM_);
    } else if (gid < PR_B_) {
        const int g = gid - PR_A_;
        const int r = g / SEGS_, s = g - r * SEGS_;
        conv_row_plain(x, xb + (size_t)r * KP_ + s * 8, r, s, MROWS_);
    } else if (gid < PR_C_) {
        const int cid = gid - PR_B_;
        const int bh  = cid / 1792;
        const int rem = cid - bh * 1792;
        const int row = 65 + rem / 256;
        const int tc  = rem - (row - 65) * 256;
        const unsigned val = (row == 65) ? 0x3F803F80u : 0u;
        unsigned* p = (unsigned*)(VT + ((size_t)bh * VTR_ + row) * T_ + tc * 8);
        p[0] = val; p[1] = val; p[2] = val; p[3] = val;
    } else {
        const int g = gid - PR_C_;
        const int r = g / SEGS_, s = g - r * SEGS_;
        conv_row_plain(Wp, WpB + (size_t)r * KP_ + s * 8, r, s, DIM_);
    }
}

// ---------------------------------------------------------------------------
// global->LDS async 16B
// ---------------------------------------------------------------------------
__device__ __forceinline__ void gload_lds16(const void* g, void* l) {
    __builtin_amdgcn_global_load_lds(
        (const __attribute__((address_space(1))) void*)g,
        (__attribute__((address_space(3))) void*)l, 16, 0, 0);
}

// ---------------------------------------------------------------------------
// PURE GEMM core 128x128 (both operands bf16, row stride KP_):
// barrier / 12x global_load_lds / barrier / 48 MFMA per 96-wide K-step.
// ---------------------------------------------------------------------------
#define GEMM_PURE_CORE(Ac_, Bw_, N0_, M0_)                                    \
    __shared__ __bf16 As[128 * 96];                                           \
    __shared__ __bf16 Bs[128 * 96];                                           \
    const int tid  = threadIdx.x;                                             \
    const int lane = tid & 63;                                                \
    const int w    = tid >> 6;                                                \
    const int wr   = (w >> 1) * 64, wc = (w & 1) * 64;                        \
    const __bf16* gap[6]; const __bf16* gb[6];                                \
    _Pragma("unroll")                                                         \
    for (int qi = 0; qi < 6; ++qi) {                                          \
        const int cid = qi * 256 + tid;                                       \
        const int rr  = cid / 12, cc = cid - rr * 12;                         \
        gap[qi] = Ac_ + (size_t)(M0_ + rr) * KP_ + cc * 8;                    \
        gb[qi]  = Bw_ + (size_t)(N0_ + rr) * KP_ + cc * 8;                    \
    }                                                                         \
    f32x4 acc[4][4];                                                          \
    _Pragma("unroll")                                                         \
    for (int i = 0; i < 4; ++i)                                               \
        _Pragma("unroll")                                                     \
        for (int j = 0; j < 4; ++j) acc[i][j] = (f32x4){0.f, 0.f, 0.f, 0.f};  \
    const __bf16* pa = As + (wr + (lane & 15)) * 96 + (lane >> 4) * 8;        \
    const __bf16* pb = Bs + (wc + (lane & 15)) * 96 + (lane >> 4) * 8;        \
    for (int k0 = 0; k0 < KP_; k0 += 96) {                                    \
        __syncthreads();                                                      \
        _Pragma("unroll")                                                     \
        for (int qi = 0; qi < 6; ++qi) {                                      \
            gload_lds16(gap[qi] + k0, As + (qi * 256 + tid) * 8);             \
            gload_lds16(gb[qi]  + k0, Bs + (qi * 256 + tid) * 8);             \
        }                                                                     \
        __syncthreads();                                                      \
        _Pragma("unroll")                                                     \
        for (int ks = 0; ks < 3; ++ks) {                                      \
            bf16x8 a[4], b[4];                                                \
            _Pragma("unroll")                                                 \
            for (int i = 0; i < 4; ++i)                                       \
                a[i] = *(const bf16x8*)(pa + i * 16 * 96 + ks * 32);          \
            _Pragma("unroll")                                                 \
            for (int j = 0; j < 4; ++j)                                       \
                b[j] = *(const bf16x8*)(pb + j * 16 * 96 + ks * 32);          \
            __builtin_amdgcn_s_setprio(1);                                    \
            _Pragma("unroll")                                                 \
            for (int i = 0; i < 4; ++i)                                       \
                _Pragma("unroll")                                             \
                for (int j = 0; j < 4; ++j)                                   \
                    acc[i][j] = __builtin_amdgcn_mfma_f32_16x16x32_bf16(      \
                        a[i], b[j], acc[i][j], 0, 0, 0);                      \
            __builtin_amdgcn_s_setprio(0);                                    \
        }                                                                     \
    }

// QKV GEMM: N=3456 (Q|K|V). Q,K -> BF16; V -> VT bf16 [bh][d][t] directly.
__global__ __launch_bounds__(256)
void gemm_qkv_b(const __bf16* __restrict__ Ac, const __bf16* __restrict__ Bw,
                __bf16* __restrict__ Cq, __bf16* __restrict__ Ck,
                __bf16* __restrict__ VTout)
{
    const int bid = blockIdx.x;
    const int gid = (bid & 7) * 108 + (bid >> 3);   // 864 = 8 * 108
    const int n0  = (gid >> 5) * 128;
    const int m0  = (gid & 31) * 128;
    GEMM_PURE_CORE(Ac, Bw, n0, m0)

    const int seg = n0 / NP_;                 // block fully inside one segment
    const int rbase = m0 + wr + (lane >> 4) * 4;
    const int cbase = n0 - seg * NP_ + wc + (lane & 15);

    if (seg < 2) {
        __bf16* C = seg ? Ck : Cq;
        #pragma unroll
        for (int i = 0; i < 4; ++i)
            #pragma unroll
            for (int j = 0; j < 4; ++j) {
                const int n = cbase + j * 16;
                if (n < DIM_) {
                    #pragma unroll
                    for (int r = 0; r < 4; ++r)
                        C[(size_t)(rbase + i * 16 + r) * DIM_ + n] =
                            (__bf16)acc[i][j][r];
                }
            }
    } else {
        #pragma unroll
        for (int i = 0; i < 4; ++i) {
            const int tg = rbase + i * 16;            // mult of 4
            const int bb = tg >> 11, tt = tg & (T_ - 1);
            #pragma unroll
            for (int j = 0; j < 4; ++j) {
                const int n = cbase + j * 16;
                if (n < DIM_) {
                    const int h = n / 65, d = n - h * 65;
                    const size_t off =
                        ((size_t)(bb * H_ + h) * VTR_ + d) * T_ + tt;
                    uint2 pk;
                    pk.x = pack_bf16(acc[i][j][0], acc[i][j][1]);
                    pk.y = pack_bf16(acc[i][j][2], acc[i][j][3]);
                    *(uint2*)(VTout + off) = pk;
                }
            }
        }
    }
}

// ---------------------------------------------------------------------------
// OUT GEMM v2: 64x128 tiles, 576 blocks = 2.25/CU (vs 288 = 1.1/CU): barrier
// drains now overlap across co-resident blocks (same fix as attn v9).
// LDS 36 KB.  out fp32.
// ---------------------------------------------------------------------------
__global__ __launch_bounds__(256)
void gemm_out_b2(const __bf16* __restrict__ Ac, const __bf16* __restrict__ Bw,
                 float* __restrict__ C)
{
    __shared__ __bf16 As[64 * 96];
    __shared__ __bf16 Bs[128 * 96];
    const int tid  = threadIdx.x;
    const int lane = tid & 63;
    const int w    = tid >> 6;
    const int wr   = (w >> 1) * 32, wc = (w & 1) * 64;
    const int bid  = blockIdx.x;
    const int gid  = (bid & 7) * 72 + (bid >> 3);   // 576 = 8 * 72
    const int n0   = (gid % 9) * 128;
    const int m0   = (gid / 9) * 64;

    const __bf16* gap[3]; const __bf16* gb[6];
    #pragma unroll
    for (int qi = 0; qi < 3; ++qi) {
        const int cid = qi * 256 + tid;
        const int rr  = cid / 12, cc = cid - rr * 12;
        gap[qi] = Ac + (size_t)(m0 + rr) * KP_ + cc * 8;
    }
    #pragma unroll
    for (int qi = 0; qi < 6; ++qi) {
        const int cid = qi * 256 + tid;
        const int rr  = cid / 12, cc = cid - rr * 12;
        gb[qi] = Bw + (size_t)(n0 + rr) * KP_ + cc * 8;
    }
    f32x4 acc[2][4];
    #pragma unroll
    for (int i = 0; i < 2; ++i)
        #pragma unroll
        for (int j = 0; j < 4; ++j) acc[i][j] = (f32x4){0.f, 0.f, 0.f, 0.f};
    const __bf16* pa = As + (wr + (lane & 15)) * 96 + (lane >> 4) * 8;
    const __bf16* pb = Bs + (wc + (lane & 15)) * 96 + (lane >> 4) * 8;

    for (int k0 = 0; k0 < KP_; k0 += 96) {
        __syncthreads();
        #pragma unroll
        for (int qi = 0; qi < 3; ++qi)
            gload_lds16(gap[qi] + k0, As + (qi * 256 + tid) * 8);
        #pragma unroll
        for (int qi = 0; qi < 6; ++qi)
            gload_lds16(gb[qi] + k0, Bs + (qi * 256 + tid) * 8);
        __syncthreads();
        #pragma unroll
        for (int ks = 0; ks < 3; ++ks) {
            bf16x8 a[2], b[4];
            #pragma unroll
            for (int i = 0; i < 2; ++i)
                a[i] = *(const bf16x8*)(pa + i * 16 * 96 + ks * 32);
            #pragma unroll
            for (int j = 0; j < 4; ++j)
                b[j] = *(const bf16x8*)(pb + j * 16 * 96 + ks * 32);
            __builtin_amdgcn_s_setprio(1);
            #pragma unroll
            for (int i = 0; i < 2; ++i)
                #pragma unroll
                for (int j = 0; j < 4; ++j)
                    acc[i][j] = __builtin_amdgcn_mfma_f32_16x16x32_bf16(
                        a[i], b[j], acc[i][j], 0, 0, 0);
            __builtin_amdgcn_s_setprio(0);
        }
    }

    const int rbase = m0 + wr + (lane >> 4) * 4;
    const int cbase = n0 + wc + (lane & 15);
    #pragma unroll
    for (int i = 0; i < 2; ++i)
        #pragma unroll
        for (int j = 0; j < 4; ++j) {
            const int n = cbase + j * 16;
            if (n < DIM_) {
                #pragma unroll
                for (int r = 0; r < 4; ++r)
                    C[(size_t)(rbase + i * 16 + r) * DIM_ + n] = acc[i][j][r];
            }
        }
}

// ---------------------------------------------------------------------------
// Rotary + Lorentz-fold conversion (round-17-verified), bf16 input.
// XB[bh][t][96]:
//   Q side: cols 0..63 = SCALE*rot; col64,65 = -SCALE*c; col66 = -SCALE*a_hi.
//   K side: cols 0..63 = rot; col64 = b_hi, col65 = b_lo, col66 = b_hi.
// QK MFMA over 96 dims = SCALE*(spatial - q0k0) + per-row const (cancels).
// ---------------------------------------------------------------------------
__global__ __launch_bounds__(256)
void rotary2(const __bf16* __restrict__ Xq, const __bf16* __restrict__ Xk,
             __bf16* __restrict__ QB, __bf16* __restrict__ KB)
{
    const int gwid = (blockIdx.x * 256 + threadIdx.x) >> 6;  // 0..131071
    const int lane = threadIdx.x & 63;
    const int which = gwid >> 16;          // 0 = q, 1 = k
    const int wid   = gwid & 65535;

    const float SCALE = 0.18033688f;       // log2(e)/8

    const int h  = wid & (H_ - 1);
    const int bt = wid >> 4;               // b*T + t
    const int t  = bt & (T_ - 1);
    const int b  = bt >> 11;
    const __bf16* base = (which ? Xk : Xq) + (size_t)bt * DIM_ + h * HD1_;

    const int j = lane & 31;
    const float pw = powf(10000.0f, (float)j * (1.0f / 32.0f));
    const float fr = (float)t * (1.0f / pw);
    const float cs = cosf(fr);
    const float sn = sinf(fr);

    const float x1 = (float)base[1 + j];
    const float x2 = (float)base[33 + j];

    float rot = (lane < 32) ? (x1 * cs + x2 * sn)
                            : (x2 * cs - x1 * sn);
    rot = fminf(fmaxf(rot, -1000.0f), 1000.0f);

    float sq = rot * rot;
    #pragma unroll
    for (int off = 32; off >= 1; off >>= 1)
        sq += __shfl_xor(sq, off, 64);
    sq = fminf(fmaxf(sq, 0.0f), 1.0e6f);

    const float x0 = sqrtf((1.0f + sq) + 1.0e-6f);

    __bf16* XB = which ? KB : QB;
    const size_t base96 = (size_t)((b * H_ + h) * T_ + t) * QKW_;
    XB[base96 + lane] = which ? (__bf16)rot : (__bf16)(SCALE * rot);

    if (lane < 32) {
        float v = 0.0f;
        const float d0 = x0 - 5.25f;
        if (which) {                       // K side: b_hi, b_lo, b_hi
            const float bh = (float)(__bf16)d0;
            if (lane == 0 || lane == 2) v = bh;
            else if (lane == 1) v = d0 - bh;
        } else {                           // Q side: -S*c, -S*c, -S*a_hi
            if (lane < 2) v = -SCALE * 5.25f;
            else if (lane == 2) v = -SCALE * (float)(__bf16)d0;
        }
        XB[base96 + 64 + lane] = (__bf16)v;
    }
}

// ---------------------------------------------------------------------------
// MFMA attention v11: v9 (QBLK=128, 2 blocks/CU sweet spot) with V double-
// buffered alongside K -> ONE barrier per tile (barrier2 removed; the Pt
// write->read is same-wave and LDS is in-order per wave; the single-barrier
// K+V dbuf pattern was correctness-proven by v5 in round 14).  LDS 62 KB
// (2 blocks/CU preserved: 2x62=124 < 160).  bid%8 = bh%8 (XCD locality).
// ---------------------------------------------------------------------------
__global__ __launch_bounds__(256)
void attn_mfma11(const __bf16* __restrict__ QB, const __bf16* __restrict__ KB,
                 const __bf16* __restrict__ VT, __bf16* __restrict__ yb)
{
    __shared__ __bf16 Kt[2][64 * 96] __attribute__((aligned(16)));
    __shared__ __bf16 Vt[2][80 * 64] __attribute__((aligned(16)));
    __shared__ __bf16 Pt[128 * 72] __attribute__((aligned(16)));

    const int tid  = threadIdx.x;
    const int lane = tid & 63;
    const int w    = tid >> 6;
    const int lx   = lane & 15;
    const int ly   = lane >> 4;
    const int bh   = blockIdx.x;           // XCD-local: bid%8 == bh%8
    const int q0r  = blockIdx.y * 128;

    const __bf16* QBb = QB + (size_t)bh * T_ * QKW_;
    const __bf16* KBb = KB + (size_t)bh * T_ * QKW_;
    const __bf16* VTb = VT + (size_t)bh * VTR_ * T_;

    // Q fragments: registers, read once (2 tiles x 96 dims)
    bf16x8 aq[2][3];
    #pragma unroll
    for (int t = 0; t < 2; ++t)
        #pragma unroll
        for (int ks = 0; ks < 3; ++ks)
            aq[t][ks] = *(const bf16x8*)
                (QBb + (size_t)(q0r + t * 64 + w * 16 + lx) * QKW_ +
                 ks * 32 + ly * 8);

    ((unsigned*)Vt[0])[2304 + tid] = 0u;   // rows 72..79 (never re-written)
    ((unsigned*)Vt[1])[2304 + tid] = 0u;

    // K staging offsets: 768 chunks; inverse rotation swizzle on SOURCE
    int offk[3];
    #pragma unroll
    for (int qi = 0; qi < 3; ++qi) {
        const int cid = qi * 256 + tid;
        const int s = cid / 12, p = cid - s * 12;
        const int c = (p & 12) | ((p - (s >> 1)) & 3);
        offk[qi] = s * QKW_ + c * 8;       // + s0*QKW_
    }
    int offv[3];
    #pragma unroll
    for (int qi = 0; qi < 3; ++qi) {
        const int cid = qi * 256 + tid;
        const int d = cid >> 3, jj = cid & 7;
        offv[qi] = d * T_ + (jj ^ (d & 7)) * 8;   // + s0
    }

    // prologue: stage K[0] and V[0] into buffer 0
    #pragma unroll
    for (int qi = 0; qi < 3; ++qi)
        gload_lds16(KBb + offk[qi], &Kt[0][(qi * 256 + tid) * 8]);
    gload_lds16(VTb + offv[0], &Vt[0][tid * 8]);
    gload_lds16(VTb + offv[1], &Vt[0][(256 + tid) * 8]);
    if (tid < 64)
        gload_lds16(VTb + offv[2], &Vt[0][(512 + tid) * 8]);

    f32x4 acc_o[2][5];
    #pragma unroll
    for (int t = 0; t < 2; ++t)
        #pragma unroll
        for (int n = 0; n < 5; ++n) acc_o[t][n] = (f32x4){0.f, 0.f, 0.f, 0.f};

    const int rr = (ly + (lx >> 1)) & 3;   // Kt frag-read rotation

    int cur = 0;
    for (int it = 0; it < T_ / 64; ++it) {
        __syncthreads();   // buf[cur] (K+V) staged; prev iter done with buf^1

        if (it + 1 < T_ / 64) {            // prefetch K,V[it+1] into buf^1
            const int s1 = (it + 1) * 64;
            const size_t koff = (size_t)s1 * QKW_;
            #pragma unroll
            for (int qi = 0; qi < 3; ++qi)
                gload_lds16(KBb + koff + offk[qi],
                            &Kt[cur ^ 1][(qi * 256 + tid) * 8]);
            gload_lds16(VTb + s1 + offv[0], &Vt[cur ^ 1][tid * 8]);
            gload_lds16(VTb + s1 + offv[1], &Vt[cur ^ 1][(256 + tid) * 8]);
            if (tid < 64)
                gload_lds16(VTb + s1 + offv[2], &Vt[cur ^ 1][(512 + tid) * 8]);
        }

        // ---- QK^T + exp2 + Pt write, both q-tiles ----
        #pragma unroll
        for (int t = 0; t < 2; ++t) {
            f32x4 sc[4];
            __builtin_amdgcn_s_setprio(1);
            #pragma unroll
            for (int n = 0; n < 4; ++n) {
                f32x4 c = (f32x4){0.f, 0.f, 0.f, 0.f};
                #pragma unroll
                for (int ks = 0; ks < 3; ++ks) {
                    const bf16x8 bk = *(const bf16x8*)
                        &Kt[cur][(n * 16 + lx) * 96 + ks * 32 + rr * 8];
                    c = __builtin_amdgcn_mfma_f32_16x16x32_bf16(
                        aq[t][ks], bk, c, 0, 0, 0);
                }
                sc[n] = c;
            }
            __builtin_amdgcn_s_setprio(0);

            #pragma unroll
            for (int n = 0; n < 4; ++n)
                #pragma unroll
                for (int r = 0; r < 4; ++r)
                    Pt[(t * 64 + w * 16 + ly * 4 + r) * 72 + n * 16 + lx] =
                        (__bf16)exp2_fast(sc[n][r]);
        }

        // ---- PV, both q-tiles (same-wave Pt read; LDS in-order/wave) ----
        #pragma unroll
        for (int t = 0; t < 2; ++t) {
            bf16x8 ap[2];
            #pragma unroll
            for (int ks = 0; ks < 2; ++ks)
                ap[ks] = *(const bf16x8*)
                    &Pt[(t * 64 + w * 16 + lx) * 72 + ks * 32 + ly * 8];
            __builtin_amdgcn_s_setprio(1);
            #pragma unroll
            for (int n = 0; n < 5; ++n) {
                f32x4 c = acc_o[t][n];
                #pragma unroll
                for (int ks = 0; ks < 2; ++ks) {
                    const bf16x8 bv = *(const bf16x8*)
                        &Vt[cur][(n * 16 + lx) * 64 +
                                 ((ks * 4 + ly) ^ (lx & 7)) * 8];
                    c = __builtin_amdgcn_mfma_f32_16x16x32_bf16(
                        ap[ks], bv, c, 0, 0, 0);
                }
                acc_o[t][n] = c;
            }
            __builtin_amdgcn_s_setprio(0);
        }
        cur ^= 1;
    }

    // ---- epilogue: l in acc_o[t][4][r] of lane lx==1; write yb bf16 ----
    const int b = bh >> 4, h = bh & 15;
    #pragma unroll
    for (int t = 0; t < 2; ++t)
        #pragma unroll
        for (int r = 0; r < 4; ++r) {
            const float l = __shfl(acc_o[t][4][r], (lane & 48) + 1, 64);
            const float inv = 1.0f / l;
            const int qrow = q0r + t * 64 + w * 16 + ly * 4 + r;
            __bf16* yrow = yb + (size_t)(b * T_ + qrow) * KP_ + h * HD1_;
            #pragma unroll
            for (int n = 0; n < 4; ++n)
                yrow[n * 16 + lx] = (__bf16)(acc_o[t][n][r] * inv);
            if (lx == 0) yrow[64] = (__bf16)(acc_o[t][4][r] * inv);
        }
}

// ---------------------------------------------------------------------------
// Workspace (~70 MB flat, <= 91.4 MB proven):
//  qb bf16 [4096][1040] | kb bf16 | xb bf16 (-> yb) | Wb3 | QB[.][96] |
//  KB[.][96] | VT | WpB
// ---------------------------------------------------------------------------
extern "C" void kernel_launch(void* const* d_in, const int* in_sizes, int n_in,
                              void* d_out, int out_size, void* d_ws, size_t ws_size,
                              hipStream_t stream)
{
    const float* x  = (const float*)d_in[0];
    const float* Wq = (const float*)d_in[1];
    const float* Wk = (const float*)d_in[2];
    const float* Wv = (const float*)d_in[3];
    const float* Wp = (const float*)d_in[4];

    __bf16* qb  = (__bf16*)d_ws;                       // [4096][1040]
    __bf16* kb  = qb + (size_t)MROWS_ * DIM_;          // [4096][1040]
    __bf16* xb  = kb + (size_t)MROWS_ * DIM_;          // [4096][1056], -> yb
    __bf16* Wb3 = xb + (size_t)MROWS_ * KP_;           // [3456][1056]
    __bf16* QB  = Wb3 + (size_t)NP3_ * KP_;            // [32][2048][96]
    __bf16* KB  = QB + (size_t)NBH_ * T_ * QKW_;       // [32][2048][96]
    __bf16* VT  = KB + (size_t)NBH_ * T_ * QKW_;       // [32][72][2048]
    __bf16* WpB = VT + (size_t)NBH_ * VTR_ * T_;       // [1152][1056]
    __bf16* yb  = xb;                                  // overlay

    float* out = (float*)d_out;

    dim3 blk(256);

    prep_all<<<dim3(PR_D_ / 256), blk, 0, stream>>>(
        x, Wq, Wk, Wv, Wp, xb, Wb3, VT, WpB);
    gemm_qkv_b<<<dim3(864), blk, 0, stream>>>(xb, Wb3, qb, kb, VT);

    rotary2<<<dim3(2 * (B_ * T_ * H_) / 4), blk, 0, stream>>>(qb, kb, QB, KB);

    attn_mfma11<<<dim3(NBH_, T_ / 128), blk, 0, stream>>>(QB, KB, VT, yb);

    gemm_out_b2<<<dim3(576), blk, 0, stream>>>(yb, WpB, out);
}